// Round 3
// baseline (381.337 us; speedup 1.0000x reference)
//
#include <hip/hip_runtime.h>

#define NTHREADS 256

typedef __attribute__((ext_vector_type(8))) short bf16x8;
typedef __attribute__((ext_vector_type(4))) short short4v;
typedef __attribute__((ext_vector_type(4))) float f32x4;

constexpr int kB = 16;
constexpr int kS = 2048;
constexpr int kD = 128;
constexpr int QBLK = 64;
constexpr int KBLK = 64;
constexpr float kNegMax = -3.402823466e38f;

// fp32 -> bf16 round-to-nearest-even
__device__ __forceinline__ short f2bf(float f) {
    unsigned u = __builtin_bit_cast(unsigned, f);
    u += 0x7FFFu + ((u >> 16) & 1u);
    return (short)(u >> 16);
}

// K/P swizzle: key = row&7 (reads have l15 in row low bits -> 8 values). G4/T2.
#define SWZ(bytecol, row) ((bytecol) ^ (((row) & 7) << 4))
// VT swizzle: write rows advance by 4 (dg*4+jj), read rows by 1 (d*16+l15).
// key = (row&7) ^ ((row>>2)&7) gives 8 distinct key values for BOTH patterns
// (slot-count verified: 8 lanes per bank-group = structural min on each side).
#define SWZV(bytecol, row) ((bytecol) ^ (((((row) & 7) ^ (((row) >> 2) & 7)) & 7) << 4))

__global__ __launch_bounds__(NTHREADS, 2)
void attn_fwd(const float* __restrict__ q, const float* __restrict__ k,
              const float* __restrict__ v, const int* __restrict__ mask,
              float* __restrict__ out)
{
    // LDS: K 16K | Vt 16K | P 8K | mask(bitpacked) 512B = 41 KiB
    __shared__ __align__(16) char smem[41472];
    char* K_lds  = smem;              // [64 kv][128 d] bf16, stride 256 B, SWZ
    char* VT_lds = smem + 16384;      // [128 d][64 kv] bf16, stride 128 B, SWZV
    char* P_lds  = smem + 32768;      // [4 waves][16 q][64 kv] bf16, stride 128 B, SWZ
    unsigned long long* M_lds = (unsigned long long*)(smem + 40960); // [64 q] bitmasks

    const int tid  = threadIdx.x;
    const int lane = tid & 63;
    const int w    = tid >> 6;   // wave 0..3, owns q-rows w*16..w*16+15
    const int l15  = lane & 15;
    const int lg   = lane >> 4;  // 0..3

    // XCD-aware swizzle: contiguous q-tiles (whole batches) per XCD.
    const int bid = (int)blockIdx.x;
    const int swz = (bid & 7) * 64 + (bid >> 3);
    const int b     = swz >> 5;
    const int qbase = (swz & 31) * QBLK;

    // ---- hoist Q fragments (pre-scaled by 1/sqrt(D)) ----
    const float scale = 0.08838834764831845f;
    bf16x8 qf[4];
    {
        const float* qp = q + ((size_t)(b * kS + qbase + w * 16 + l15)) * kD;
        #pragma unroll
        for (int kk = 0; kk < 4; ++kk) {
            const float4* p = (const float4*)(qp + kk * 32 + lg * 8);
            float4 a = p[0], c = p[1];
            bf16x8 f;
            f[0]=f2bf(a.x*scale); f[1]=f2bf(a.y*scale); f[2]=f2bf(a.z*scale); f[3]=f2bf(a.w*scale);
            f[4]=f2bf(c.x*scale); f[5]=f2bf(c.y*scale); f[6]=f2bf(c.z*scale); f[7]=f2bf(c.w*scale);
            qf[kk] = f;
        }
    }

    f32x4 acc[8];
    #pragma unroll
    for (int d = 0; d < 8; ++d) acc[d] = f32x4{0.f, 0.f, 0.f, 0.f};
    float m_r[4] = {kNegMax, kNegMax, kNegMax, kNegMax};
    float l_r[4] = {0.f, 0.f, 0.f, 0.f};

    const float* kbat = k + (size_t)b * kS * kD;
    const float* vbat = v + (size_t)b * kS * kD;
    const int* mbat = mask + ((size_t)b * kS + qbase) * kS;

    for (int kt0 = 0; kt0 < kS; kt0 += KBLK) {
        __syncthreads();  // previous tile's LDS reads done before overwrite

        // ---- stage K tile: fp32 -> bf16, [64][128], SWZ ----
        #pragma unroll
        for (int c = 0; c < 4; ++c) {
            int chunk = c * 256 + tid;          // 1024 chunks of 8 floats
            int row = chunk >> 4, col8 = chunk & 15;
            const float4* p = (const float4*)(kbat + (size_t)(kt0 + row) * kD + col8 * 8);
            float4 a = p[0], bb = p[1];
            bf16x8 f;
            f[0]=f2bf(a.x);  f[1]=f2bf(a.y);  f[2]=f2bf(a.z);  f[3]=f2bf(a.w);
            f[4]=f2bf(bb.x); f[5]=f2bf(bb.y); f[6]=f2bf(bb.z); f[7]=f2bf(bb.w);
            *(bf16x8*)(K_lds + row * 256 + SWZ(col8 * 16, row)) = f;
        }

        // ---- stage V transposed via 4x4 register-block transpose ----
        // thread handles two 4k x 4d blocks; coalesced float4 loads,
        // conflict-free short4 (8B) swizzled writes.
        #pragma unroll
        for (int it = 0; it < 2; ++it) {
            int blk = it * 256 + tid;           // 512 blocks: kg 0..15, dg 0..31
            int kg = blk >> 5, dg = blk & 31;
            float4 a0 = *(const float4*)(vbat + (size_t)(kt0 + kg * 4 + 0) * kD + dg * 4);
            float4 a1 = *(const float4*)(vbat + (size_t)(kt0 + kg * 4 + 1) * kD + dg * 4);
            float4 a2 = *(const float4*)(vbat + (size_t)(kt0 + kg * 4 + 2) * kD + dg * 4);
            float4 a3 = *(const float4*)(vbat + (size_t)(kt0 + kg * 4 + 3) * kD + dg * 4);
            #pragma unroll
            for (int jj = 0; jj < 4; ++jj) {
                int row = dg * 4 + jj;          // VT row = d
                short4v sh;
                sh[0] = f2bf((&a0.x)[jj]);
                sh[1] = f2bf((&a1.x)[jj]);
                sh[2] = f2bf((&a2.x)[jj]);
                sh[3] = f2bf((&a3.x)[jj]);
                *(short4v*)(VT_lds + row * 128 + SWZV(kg * 8, row)) = sh;
            }
        }

        // ---- stage mask: 64 q-rows -> 1-bit packed uint64 via ballot ----
        #pragma unroll
        for (int rr = 0; rr < 16; ++rr) {
            int mrow = w * 16 + rr;
            int mv = mbat[(size_t)mrow * kS + kt0 + lane];
            unsigned long long bm = __ballot(mv != 0);
            if (lane == 0) M_lds[mrow] = bm;
        }
        __syncthreads();

        // ---- S = Q @ K^T (per wave: 16 q-rows x 64 kv) ----
        f32x4 s[4];
        #pragma unroll
        for (int kt = 0; kt < 4; ++kt) {
            f32x4 z = f32x4{0.f, 0.f, 0.f, 0.f};
            int krow = kt * 16 + l15;
            #pragma unroll
            for (int kk = 0; kk < 4; ++kk) {
                bf16x8 kf = *(const bf16x8*)(K_lds + krow * 256 + SWZ(kk * 64 + lg * 16, krow));
                z = __builtin_amdgcn_mfma_f32_16x16x32_bf16(qf[kk], kf, z, 0, 0, 0);
            }
            s[kt] = z;
        }

        // ---- mask + online softmax; lane holds S[row=lg*4+i][col=kt*16+l15] ----
        #pragma unroll
        for (int i = 0; i < 4; ++i) {
            int mrow = w * 16 + lg * 4 + i;
            unsigned long long bm = M_lds[mrow] >> l15;  // broadcast read
            #pragma unroll
            for (int kt = 0; kt < 4; ++kt) {
                if ((bm >> (kt * 16)) & 1ull) s[kt][i] = kNegMax;
            }
            float mx = fmaxf(fmaxf(s[0][i], s[1][i]), fmaxf(s[2][i], s[3][i]));
            mx = fmaxf(mx, __shfl_xor(mx, 1));
            mx = fmaxf(mx, __shfl_xor(mx, 2));
            mx = fmaxf(mx, __shfl_xor(mx, 4));
            mx = fmaxf(mx, __shfl_xor(mx, 8));
            float mnew = fmaxf(m_r[i], mx);
            float corr = __expf(m_r[i] - mnew);
            m_r[i] = mnew;
            float rsum = 0.f;
            int prow = lg * 4 + i;
            #pragma unroll
            for (int kt = 0; kt < 4; ++kt) {
                float p = __expf(s[kt][i] - mnew);
                rsum += p;
                *(short*)(P_lds + w * 2048 + prow * 128 + SWZ((kt * 16 + l15) * 2, prow)) = f2bf(p);
            }
            rsum += __shfl_xor(rsum, 1);
            rsum += __shfl_xor(rsum, 2);
            rsum += __shfl_xor(rsum, 4);
            rsum += __shfl_xor(rsum, 8);
            l_r[i] = l_r[i] * corr + rsum;
            #pragma unroll
            for (int d = 0; d < 8; ++d) acc[d][i] *= corr;
        }

        // ---- O += P @ V (P from own wave's LDS, V^T contiguous b128 reads) ----
        #pragma unroll
        for (int kk = 0; kk < 2; ++kk) {
            bf16x8 pf = *(const bf16x8*)(P_lds + w * 2048 + l15 * 128 + SWZ(kk * 64 + lg * 16, l15));
            #pragma unroll
            for (int d = 0; d < 8; ++d) {
                int vrow = d * 16 + l15;
                bf16x8 vf = *(const bf16x8*)(VT_lds + vrow * 128 + SWZV(kk * 64 + lg * 16, vrow));
                acc[d] = __builtin_amdgcn_mfma_f32_16x16x32_bf16(pf, vf, acc[d], 0, 0, 0);
            }
        }
    }

    // ---- epilogue: normalize and store ----
    #pragma unroll
    for (int i = 0; i < 4; ++i) {
        float inv = 1.0f / l_r[i];
        float* op = out + ((size_t)(b * kS + qbase + w * 16 + lg * 4 + i)) * kD + l15;
        #pragma unroll
        for (int d = 0; d < 8; ++d) op[d * 16] = acc[d][i] * inv;
    }
}

extern "C" void kernel_launch(void* const* d_in, const int* in_sizes, int n_in,
                              void* d_out, int out_size, void* d_ws, size_t ws_size,
                              hipStream_t stream) {
    const float* q = (const float*)d_in[0];
    const float* k = (const float*)d_in[1];
    const float* v = (const float*)d_in[2];
    const int* mask = (const int*)d_in[3];
    float* out = (float*)d_out;
    dim3 grid(kB * (kS / QBLK));   // 512 blocks
    dim3 block(NTHREADS);
    attn_fwd<<<grid, block, 0, stream>>>(q, k, v, mask, out);
}

// Round 4
// 131.196 us; speedup vs baseline: 2.9066x; 2.9066x over previous
//
#include <hip/hip_runtime.h>

#define NTHREADS 256

typedef __attribute__((ext_vector_type(8))) short bf16x8;
typedef __attribute__((ext_vector_type(4))) short short4v;
typedef __attribute__((ext_vector_type(4))) float f32x4;

constexpr int kB = 16;
constexpr int kS = 2048;
constexpr int kD = 128;
constexpr int QBLK = 64;
constexpr int KBLK = 64;
constexpr int NTILES = kS / KBLK;   // 32
constexpr int MSTRIDE = 68;         // padded mask row stride: broadcast-only reads
constexpr float kNegMax = -3.402823466e38f;

// fp32 -> bf16 round-to-nearest-even
__device__ __forceinline__ short f2bf(float f) {
    unsigned u = __builtin_bit_cast(unsigned, f);
    u += 0x7FFFu + ((u >> 16) & 1u);
    return (short)(u >> 16);
}

// K/P swizzle: key = row&7 (G4/T2).
#define SWZ(bytecol, row) ((bytecol) ^ (((row) & 7) << 4))
// VT swizzle: write rows advance by 4, read rows by 1; key=(row&7)^((row>>2)&7)
// gives 8 distinct keys on both patterns (slot-count = structural min).
#define SWZV(bytecol, row) ((bytecol) ^ (((((row) & 7) ^ (((row) >> 2) & 7)) & 7) << 4))

__global__ __launch_bounds__(NTHREADS, 2)
void attn_fwd(const float* __restrict__ q, const float* __restrict__ k,
              const float* __restrict__ v, const int* __restrict__ mask,
              float* __restrict__ out)
{
    // LDS: K 16K | Vt 16K | P 8K | mask 64x68 = 45312 B total
    __shared__ __align__(16) char smem[45312];
    char* K_lds  = smem;              // [64 kv][128 d] bf16, stride 256 B, SWZ
    char* VT_lds = smem + 16384;      // [128 d][64 kv] bf16, stride 128 B, SWZV
    char* P_lds  = smem + 32768;      // [4 waves][16 q][64 kv] bf16, stride 128 B, SWZ
    unsigned char* M_lds = (unsigned char*)(smem + 40960);  // [64 q][68] bytes

    const int tid  = threadIdx.x;
    const int lane = tid & 63;
    const int w    = tid >> 6;   // wave 0..3, owns q-rows w*16..w*16+15
    const int l15  = lane & 15;
    const int lg   = lane >> 4;  // 0..3

    // XCD-aware swizzle: contiguous q-tiles (whole batches) per XCD.
    const int bid = (int)blockIdx.x;
    const int swz = (bid & 7) * 64 + (bid >> 3);
    const int b     = swz >> 5;
    const int qbase = (swz & 31) * QBLK;

    // ---- hoist Q fragments (pre-scaled by 1/sqrt(D)) ----
    const float scale = 0.08838834764831845f;
    bf16x8 qf[4];
    {
        const float* qp = q + ((size_t)(b * kS + qbase + w * 16 + l15)) * kD;
        #pragma unroll
        for (int kk = 0; kk < 4; ++kk) {
            const float4* p = (const float4*)(qp + kk * 32 + lg * 8);
            float4 a = p[0], c = p[1];
            bf16x8 f;
            f[0]=f2bf(a.x*scale); f[1]=f2bf(a.y*scale); f[2]=f2bf(a.z*scale); f[3]=f2bf(a.w*scale);
            f[4]=f2bf(c.x*scale); f[5]=f2bf(c.y*scale); f[6]=f2bf(c.z*scale); f[7]=f2bf(c.w*scale);
            qf[kk] = f;
        }
    }

    f32x4 acc[8];
    #pragma unroll
    for (int d = 0; d < 8; ++d) acc[d] = f32x4{0.f, 0.f, 0.f, 0.f};
    float m_r[4] = {kNegMax, kNegMax, kNegMax, kNegMax};
    float l_r[4] = {0.f, 0.f, 0.f, 0.f};

    const float* kbat = k + (size_t)b * kS * kD;
    const float* vbat = v + (size_t)b * kS * kD;
    const int* mbat = mask + ((size_t)b * kS + qbase) * kS;

    // ---- T14 prefetch registers (tile in flight) ----
    float4 kreg[4][2];   // K: 4 chunks x 8 floats
    float4 vreg[2][4];   // V: 2 blocks x 4 rows
    int4   mreg[4];      // mask: 4 int4 (independent, coalesced)

    auto LOAD = [&](int kt0) {
        #pragma unroll
        for (int c = 0; c < 4; ++c) {
            int chunk = c * 256 + tid;
            int row = chunk >> 4, col8 = chunk & 15;
            const float4* p = (const float4*)(kbat + (size_t)(kt0 + row) * kD + col8 * 8);
            kreg[c][0] = p[0];
            kreg[c][1] = p[1];
        }
        #pragma unroll
        for (int it = 0; it < 2; ++it) {
            int blk = it * 256 + tid;
            int kg = blk >> 5, dg = blk & 31;
            #pragma unroll
            for (int r = 0; r < 4; ++r)
                vreg[it][r] = *(const float4*)(vbat + (size_t)(kt0 + kg * 4 + r) * kD + dg * 4);
        }
        #pragma unroll
        for (int c = 0; c < 4; ++c) {
            int idx = c * 256 + tid;
            int mrow = idx >> 4, mc4 = idx & 15;
            mreg[c] = *(const int4*)(mbat + (size_t)mrow * kS + kt0 + mc4 * 4);
        }
    };

    auto STORE = [&]() {
        #pragma unroll
        for (int c = 0; c < 4; ++c) {
            int chunk = c * 256 + tid;
            int row = chunk >> 4, col8 = chunk & 15;
            bf16x8 f;
            f[0]=f2bf(kreg[c][0].x); f[1]=f2bf(kreg[c][0].y);
            f[2]=f2bf(kreg[c][0].z); f[3]=f2bf(kreg[c][0].w);
            f[4]=f2bf(kreg[c][1].x); f[5]=f2bf(kreg[c][1].y);
            f[6]=f2bf(kreg[c][1].z); f[7]=f2bf(kreg[c][1].w);
            *(bf16x8*)(K_lds + row * 256 + SWZ(col8 * 16, row)) = f;
        }
        #pragma unroll
        for (int it = 0; it < 2; ++it) {
            int blk = it * 256 + tid;
            int kg = blk >> 5, dg = blk & 31;
            #pragma unroll
            for (int jj = 0; jj < 4; ++jj) {
                int row = dg * 4 + jj;
                short4v sh;
                sh[0] = f2bf((&vreg[it][0].x)[jj]);
                sh[1] = f2bf((&vreg[it][1].x)[jj]);
                sh[2] = f2bf((&vreg[it][2].x)[jj]);
                sh[3] = f2bf((&vreg[it][3].x)[jj]);
                *(short4v*)(VT_lds + row * 128 + SWZV(kg * 8, row)) = sh;
            }
        }
        #pragma unroll
        for (int c = 0; c < 4; ++c) {
            int idx = c * 256 + tid;
            int mrow = idx >> 4, mc4 = idx & 15;
            unsigned pk = (unsigned)(mreg[c].x != 0)
                        | ((unsigned)(mreg[c].y != 0) << 8)
                        | ((unsigned)(mreg[c].z != 0) << 16)
                        | ((unsigned)(mreg[c].w != 0) << 24);
            *(unsigned*)(M_lds + mrow * MSTRIDE + mc4 * 4) = pk;
        }
    };

    LOAD(0);

    for (int t = 0; t < NTILES; ++t) {
        __syncthreads();   // all reads of previous tile's LDS done
        STORE();           // regs (tile t) -> LDS; vmcnt waits happen here
        __syncthreads();   // tile t visible
        if (t + 1 < NTILES) LOAD((t + 1) * KBLK);  // issue next tile, no wait

        // ---- S = Q @ K^T (per wave: 16 q-rows x 64 kv) ----
        f32x4 s[4];
        #pragma unroll
        for (int kt = 0; kt < 4; ++kt) {
            f32x4 z = f32x4{0.f, 0.f, 0.f, 0.f};
            int krow = kt * 16 + l15;
            #pragma unroll
            for (int kk = 0; kk < 4; ++kk) {
                bf16x8 kf = *(const bf16x8*)(K_lds + krow * 256 + SWZ(kk * 64 + lg * 16, krow));
                z = __builtin_amdgcn_mfma_f32_16x16x32_bf16(qf[kk], kf, z, 0, 0, 0);
            }
            s[kt] = z;
        }

        // ---- mask + online softmax; lane holds S[row=lg*4+i][col=kt*16+l15] ----
        #pragma unroll
        for (int i = 0; i < 4; ++i) {
            int mrow = w * 16 + lg * 4 + i;
            #pragma unroll
            for (int kt = 0; kt < 4; ++kt) {
                if (M_lds[mrow * MSTRIDE + kt * 16 + l15]) s[kt][i] = kNegMax;
            }
            float mx = fmaxf(fmaxf(s[0][i], s[1][i]), fmaxf(s[2][i], s[3][i]));
            mx = fmaxf(mx, __shfl_xor(mx, 1));
            mx = fmaxf(mx, __shfl_xor(mx, 2));
            mx = fmaxf(mx, __shfl_xor(mx, 4));
            mx = fmaxf(mx, __shfl_xor(mx, 8));
            float mnew = fmaxf(m_r[i], mx);
            float corr = __expf(m_r[i] - mnew);
            m_r[i] = mnew;
            float rsum = 0.f;
            int prow = lg * 4 + i;
            #pragma unroll
            for (int kt = 0; kt < 4; ++kt) {
                float p = __expf(s[kt][i] - mnew);
                rsum += p;
                *(short*)(P_lds + w * 2048 + prow * 128 + SWZ((kt * 16 + l15) * 2, prow)) = f2bf(p);
            }
            rsum += __shfl_xor(rsum, 1);
            rsum += __shfl_xor(rsum, 2);
            rsum += __shfl_xor(rsum, 4);
            rsum += __shfl_xor(rsum, 8);
            l_r[i] = l_r[i] * corr + rsum;
            #pragma unroll
            for (int d = 0; d < 8; ++d) acc[d][i] *= corr;
        }

        // ---- O += P @ V (P from own wave's LDS, V^T contiguous b128 reads) ----
        #pragma unroll
        for (int kk = 0; kk < 2; ++kk) {
            bf16x8 pf = *(const bf16x8*)(P_lds + w * 2048 + l15 * 128 + SWZ(kk * 64 + lg * 16, l15));
            #pragma unroll
            for (int d = 0; d < 8; ++d) {
                int vrow = d * 16 + l15;
                bf16x8 vf = *(const bf16x8*)(VT_lds + vrow * 128 + SWZV(kk * 64 + lg * 16, vrow));
                acc[d] = __builtin_amdgcn_mfma_f32_16x16x32_bf16(pf, vf, acc[d], 0, 0, 0);
            }
        }
    }

    // ---- epilogue: normalize and store ----
    #pragma unroll
    for (int i = 0; i < 4; ++i) {
        float inv = 1.0f / l_r[i];
        float* op = out + ((size_t)(b * kS + qbase + w * 16 + lg * 4 + i)) * kD + l15;
        #pragma unroll
        for (int d = 0; d < 8; ++d) op[d * 16] = acc[d][i] * inv;
    }
}

extern "C" void kernel_launch(void* const* d_in, const int* in_sizes, int n_in,
                              void* d_out, int out_size, void* d_ws, size_t ws_size,
                              hipStream_t stream) {
    const float* q = (const float*)d_in[0];
    const float* k = (const float*)d_in[1];
    const float* v = (const float*)d_in[2];
    const int* mask = (const int*)d_in[3];
    float* out = (float*)d_out;
    dim3 grid(kB * (kS / QBLK));   // 512 blocks
    dim3 block(NTHREADS);
    attn_fwd<<<grid, block, 0, stream>>>(q, k, v, mask, out);
}